// Round 1
// baseline (234.827 us; speedup 1.0000x reference)
//
#include <hip/hip_runtime.h>
#include <math.h>

#define EMBED 768
#define SEQ   2048
#define NB    8
#define SQRT_E 27.712812921102035f   // sqrt(768), folded into q

// ---------------------------------------------------------------------------
// Kernel 1: fused QKV projection.  out[r, j] = sum_e x[r,e] * W[j][e]
// M = 16384 rows, N = 192 cols (q|k|v stacked), K = 768.
// Block: 256 threads, tile 64 rows x 192 cols, K-chunks of 32.
// Thread micro-tile: 4 rows x 12 cols (tr = t>>4 in 0..15, tc = t&15).
// q output pre-scaled by sqrt(768) so attention scores need no extra scale.
// ---------------------------------------------------------------------------
__global__ __launch_bounds__(256)
void proj_kernel(const float* __restrict__ x,
                 const float* __restrict__ Wq,
                 const float* __restrict__ Wk,
                 const float* __restrict__ Wv,
                 float* __restrict__ qo,
                 float* __restrict__ ko,
                 float* __restrict__ vo)
{
    __shared__ float At[32][68];    // At[e][r], padded stride 68 (16B-aligned rows)
    __shared__ float Bt[32][196];   // Bt[e][j], padded stride 196

    const int t    = threadIdx.x;
    const int row0 = blockIdx.x * 64;
    const int tr   = t >> 4;   // 0..15 -> rows tr*4 .. tr*4+3
    const int tc   = t & 15;   // 0..15 -> cols tc*12 .. tc*12+11

    float acc[4][12];
#pragma unroll
    for (int i = 0; i < 4; ++i)
#pragma unroll
        for (int c = 0; c < 12; ++c) acc[i][c] = 0.f;

    for (int e0 = 0; e0 < EMBED; e0 += 32) {
        __syncthreads();
        // stage x chunk (64 rows x 32 e), transposed into At[e][r]
#pragma unroll
        for (int it = 0; it < 8; ++it) {
            int idx = t + it * 256;
            int r = idx >> 5, e = idx & 31;
            At[e][r] = x[(size_t)(row0 + r) * EMBED + e0 + e];
        }
        // stage W chunk (192 j x 32 e), transposed into Bt[e][j]
#pragma unroll
        for (int it = 0; it < 24; ++it) {
            int idx = t + it * 256;
            int j = idx >> 5, e = idx & 31;
            const float* W = (j < 64) ? Wq : (j < 128) ? Wk : Wv;
            Bt[e][j] = W[(size_t)(j & 63) * EMBED + e0 + e];
        }
        __syncthreads();
#pragma unroll
        for (int e = 0; e < 32; ++e) {
            float4 a  = *(const float4*)&At[e][tr * 4];
            float4 b0 = *(const float4*)&Bt[e][tc * 12];
            float4 b1 = *(const float4*)&Bt[e][tc * 12 + 4];
            float4 b2 = *(const float4*)&Bt[e][tc * 12 + 8];
            const float av[4]  = {a.x, a.y, a.z, a.w};
            const float bv[12] = {b0.x, b0.y, b0.z, b0.w,
                                  b1.x, b1.y, b1.z, b1.w,
                                  b2.x, b2.y, b2.z, b2.w};
#pragma unroll
            for (int i = 0; i < 4; ++i)
#pragma unroll
                for (int c = 0; c < 12; ++c)
                    acc[i][c] = fmaf(av[i], bv[c], acc[i][c]);
        }
    }

    // epilogue: scatter to q/k/v (q gets the sqrt(E) score scale folded in)
#pragma unroll
    for (int i = 0; i < 4; ++i) {
        size_t R = (size_t)(row0 + tr * 4 + i);
#pragma unroll
        for (int c = 0; c < 12; ++c) {
            int j = tc * 12 + c;
            float val = acc[i][c];
            if (j < 64)       qo[R * 64 + j]         = val * SQRT_E;
            else if (j < 128) ko[R * 64 + (j - 64)]  = val;
            else              vo[R * 64 + (j - 128)] = val;
        }
    }
}

// ---------------------------------------------------------------------------
// Kernel 2: causal flash attention, fp32.
// Q-tile = 32 rows, K-tile = 64 cols. Block = 256 threads as 8 (tr) x 32 (tc),
// micro-tile 4 rows x 2 cols. Each block does the balanced q-tile pair
// (pair, 63 - pair): (pair/2+1) + ((63-pair)/2+1) = 33 k-tiles always.
// Online softmax; row reductions via __shfl_xor over the 32-lane tc group.
// ---------------------------------------------------------------------------
__global__ __launch_bounds__(256)
void attn_kernel(const float* __restrict__ qg,
                 const float* __restrict__ kg,
                 const float* __restrict__ vg,
                 float* __restrict__ out)
{
    __shared__ float qT[64][36];   // [h][i]  (i < 32)
    __shared__ float kT[64][68];   // [h][j]  (j < 64)
    __shared__ float vT[64][68];   // [j][h]
    __shared__ float pT[64][36];   // [j][i]

    const int t      = threadIdx.x;
    const int b      = blockIdx.x >> 5;   // batch 0..7
    const int pairid = blockIdx.x & 31;   // 0..31
    const int tr     = t >> 5;            // 0..7  -> rows tr*4 .. +3
    const int tc     = t & 31;            // 0..31 -> cols tc*2, tc*2+1

    const float* qb = qg + (size_t)b * SEQ * 64;
    const float* kb = kg + (size_t)b * SEQ * 64;
    const float* vb = vg + (size_t)b * SEQ * 64;
    float*       ob = out + (size_t)b * SEQ * 64;

    for (int half = 0; half < 2; ++half) {
        const int qt = half ? (63 - pairid) : pairid;  // q-tile index (32 rows)
        const int r0 = qt * 32;

        __syncthreads();   // protect LDS reuse across halves
        // stage q tile (32 x 64) transposed, scale already folded in
#pragma unroll
        for (int it = 0; it < 8; ++it) {
            int idx = t + it * 256;
            int i = idx >> 6, h = idx & 63;
            qT[h][i] = qb[(size_t)(r0 + i) * 64 + h];
        }

        float o[4][2];
        float m_run[4], l_run[4];
#pragma unroll
        for (int i = 0; i < 4; ++i) {
            o[i][0] = o[i][1] = 0.f;
            m_run[i] = -INFINITY;
            l_run[i] = 0.f;
        }

        const int nt = qt / 2 + 1;   // k-tiles needed for causal coverage
        for (int jt = 0; jt < nt; ++jt) {
            const int j0 = jt * 64;
            __syncthreads();   // prev PV reads of kT/vT/pT done
#pragma unroll
            for (int it = 0; it < 16; ++it) {
                int idx = t + it * 256;
                int j = idx >> 6, h = idx & 63;
                kT[h][j] = kb[(size_t)(j0 + j) * 64 + h];
                vT[j][h] = vb[(size_t)(j0 + j) * 64 + h];
            }
            __syncthreads();

            // scores: s[i][c] = q_row(r0+4tr+i) . k_row(j0+2tc+c)
            float s[4][2];
#pragma unroll
            for (int i = 0; i < 4; ++i) { s[i][0] = 0.f; s[i][1] = 0.f; }
#pragma unroll
            for (int h = 0; h < 64; ++h) {
                float4 a  = *(const float4*)&qT[h][tr * 4];
                float2 bb = *(const float2*)&kT[h][tc * 2];
                const float av[4] = {a.x, a.y, a.z, a.w};
#pragma unroll
                for (int i = 0; i < 4; ++i) {
                    s[i][0] = fmaf(av[i], bb.x, s[i][0]);
                    s[i][1] = fmaf(av[i], bb.y, s[i][1]);
                }
            }

            // causal mask: only the last tile can touch the diagonal
            if (jt == nt - 1) {
#pragma unroll
                for (int i = 0; i < 4; ++i) {
                    int row = r0 + tr * 4 + i;
#pragma unroll
                    for (int c = 0; c < 2; ++c) {
                        int col = j0 + tc * 2 + c;
                        if (col > row) s[i][c] = -INFINITY;
                    }
                }
            }

            // online softmax (per row, reduce over the 32-lane tc group)
#pragma unroll
            for (int i = 0; i < 4; ++i) {
                float mt = fmaxf(s[i][0], s[i][1]);
#pragma unroll
                for (int d = 1; d < 32; d <<= 1)
                    mt = fmaxf(mt, __shfl_xor(mt, d));
                float mn   = fmaxf(m_run[i], mt);
                float corr = __expf(m_run[i] - mn);   // exp(-inf)=0 on first tile
                float p0 = __expf(s[i][0] - mn);
                float p1 = __expf(s[i][1] - mn);
                float lt = p0 + p1;
#pragma unroll
                for (int d = 1; d < 32; d <<= 1)
                    lt += __shfl_xor(lt, d);
                m_run[i] = mn;
                l_run[i] = l_run[i] * corr + lt;
                o[i][0] *= corr;
                o[i][1] *= corr;
                s[i][0] = p0;
                s[i][1] = p1;
            }

            // write P^T for the PV GEMM
            {
                float4 p0 = make_float4(s[0][0], s[1][0], s[2][0], s[3][0]);
                float4 p1 = make_float4(s[0][1], s[1][1], s[2][1], s[3][1]);
                *(float4*)&pT[tc * 2][tr * 4]     = p0;
                *(float4*)&pT[tc * 2 + 1][tr * 4] = p1;
            }
            __syncthreads();

            // PV: o[i][c] += sum_j P[i][j] * v[j][2tc+c]
#pragma unroll
            for (int j = 0; j < 64; ++j) {
                float4 a  = *(const float4*)&pT[j][tr * 4];
                float2 bb = *(const float2*)&vT[j][tc * 2];
                const float av[4] = {a.x, a.y, a.z, a.w};
#pragma unroll
                for (int i = 0; i < 4; ++i) {
                    o[i][0] = fmaf(av[i], bb.x, o[i][0]);
                    o[i][1] = fmaf(av[i], bb.y, o[i][1]);
                }
            }
        }

        // normalize + store
#pragma unroll
        for (int i = 0; i < 4; ++i) {
            int row = r0 + tr * 4 + i;
            float inv = 1.0f / l_run[i];
            float2 res = make_float2(o[i][0] * inv, o[i][1] * inv);
            *(float2*)&ob[(size_t)row * 64 + tc * 2] = res;
        }
    }
}

// ---------------------------------------------------------------------------
extern "C" void kernel_launch(void* const* d_in, const int* in_sizes, int n_in,
                              void* d_out, int out_size, void* d_ws, size_t ws_size,
                              hipStream_t stream)
{
    const float* x  = (const float*)d_in[0];
    const float* Wq = (const float*)d_in[1];
    const float* Wk = (const float*)d_in[2];
    const float* Wv = (const float*)d_in[3];
    float* out = (float*)d_out;

    float* ws = (float*)d_ws;
    const size_t per = (size_t)NB * SEQ * 64;   // 1,048,576 floats
    float* q = ws;
    float* k = ws + per;
    float* v = ws + 2 * per;

    // 16384 rows / 64 rows-per-block = 256 blocks
    proj_kernel<<<dim3(256), dim3(256), 0, stream>>>(x, Wq, Wk, Wv, q, k, v);
    // 8 batches x 32 balanced q-tile pairs = 256 blocks
    attn_kernel<<<dim3(256), dim3(256), 0, stream>>>(q, k, v, out);
}

// Round 2
// 104.316 us; speedup vs baseline: 2.2511x; 2.2511x over previous
//
#include <hip/hip_runtime.h>
#include <math.h>

#define EMBED 768
#define SEQ   2048
#define NB    8
#define SQRT_E 27.712812921102035f   // sqrt(768), folded into Wq at split time

typedef short  short8 __attribute__((ext_vector_type(8)));
typedef float  f32x4  __attribute__((ext_vector_type(4)));

// ws layout (ushort element offsets)
#define WHI_OFF  0u
#define WLO_OFF  147456u
#define QHI_OFF  294912u
#define QLO_OFF  (294912u + 1u*1048576u)
#define KHI_OFF  (294912u + 2u*1048576u)
#define KLO_OFF  (294912u + 3u*1048576u)
#define VT_OFF   (294912u + 4u*1048576u)
// total = 294912 + 5*1048576 = 5,537,792 ushorts = 11,075,584 bytes

__device__ __forceinline__ ushort f2bf(float f) {
    unsigned u = __float_as_uint(f);
    return (ushort)((u + 0x7FFFu + ((u >> 16) & 1u)) >> 16);
}
__device__ __forceinline__ float bf2f(ushort h) {
    return __uint_as_float(((unsigned)h) << 16);
}

// ---------------------------------------------------------------------------
// Kernel 0: split W into bf16 hi/lo.  w rows: [0,64)=Wq*sqrt(E), [64,128)=Wk,
// [128,192)=Wv.  w_hi/w_lo are [192][768] bf16 row-major.
// ---------------------------------------------------------------------------
__global__ __launch_bounds__(256)
void split_w_kernel(const float* __restrict__ Wq, const float* __restrict__ Wk,
                    const float* __restrict__ Wv,
                    ushort* __restrict__ w_hi, ushort* __restrict__ w_lo)
{
    int idx = blockIdx.x * 256 + threadIdx.x;
    if (idx >= 192 * EMBED) return;
    int row = idx / EMBED, e = idx - row * EMBED;
    float f;
    if (row < 64)       f = Wq[row * EMBED + e] * SQRT_E;
    else if (row < 128) f = Wk[(row - 64) * EMBED + e];
    else                f = Wv[(row - 128) * EMBED + e];
    ushort hi = f2bf(f);
    w_hi[idx] = hi;
    w_lo[idx] = f2bf(f - bf2f(hi));
}

// ---------------------------------------------------------------------------
// Kernel 1: QKV projection via MFMA 16x16x32 bf16, split-bf16 (3 products) for
// q/k columns, single product for v columns.
// Block: 256 thr (4 waves as 2x2), tile M=64 x N=192, K-chunks of 32.
// Wave (wm,wn): rows wm*32 (2 m-tiles of 16), col tiles ntg = 2*nt + wn
// (interleaved so both wn slabs get 4 qk-tiles + 2 v-tiles -> balanced MFMA).
// Outputs: q_hi/q_lo, k_hi/k_lo as [b][s][64] bf16; v transposed v_t[b][64][s].
// ---------------------------------------------------------------------------
__global__ __launch_bounds__(256)
void proj_kernel(const float* __restrict__ x,
                 const ushort* __restrict__ w_hi, const ushort* __restrict__ w_lo,
                 ushort* __restrict__ q_hi, ushort* __restrict__ q_lo,
                 ushort* __restrict__ k_hi, ushort* __restrict__ k_lo,
                 ushort* __restrict__ v_t)
{
    __shared__ __align__(16) ushort xa_hi[64][40], xa_lo[64][40];   // pad 32->40
    __shared__ __align__(16) ushort wb_hi[192][40], wb_lo[192][40];

    const int t    = threadIdx.x;
    const int row0 = blockIdx.x * 64;
    const int lane = t & 63;
    const int wid  = t >> 6;
    const int wm   = wid >> 1;      // 0,1
    const int wn   = wid & 1;       // 0,1
    const int ln   = lane & 15;
    const int kg   = lane >> 4;     // 0..3

    const f32x4 vzero = {0.f, 0.f, 0.f, 0.f};
    f32x4 acc[2][6];
#pragma unroll
    for (int mt = 0; mt < 2; ++mt)
#pragma unroll
        for (int nt = 0; nt < 6; ++nt) acc[mt][nt] = vzero;

    const int srow = t >> 2;          // 0..63
    const int skk  = (t & 3) * 8;     // 0,8,16,24

    for (int e0 = 0; e0 < EMBED; e0 += 32) {
        __syncthreads();
        // stage x tile 64x32 fp32 -> hi/lo bf16
        {
            const float* xp = x + (size_t)(row0 + srow) * EMBED + e0 + skk;
            float4 f0 = *(const float4*)xp;
            float4 f1 = *(const float4*)(xp + 4);
            float fv[8] = {f0.x, f0.y, f0.z, f0.w, f1.x, f1.y, f1.z, f1.w};
            short8 vh, vl;
#pragma unroll
            for (int i = 0; i < 8; ++i) {
                ushort h = f2bf(fv[i]);
                vh[i] = (short)h;
                vl[i] = (short)f2bf(fv[i] - bf2f(h));
            }
            *(short8*)&xa_hi[srow][skk] = vh;
            *(short8*)&xa_lo[srow][skk] = vl;
        }
        // stage W tile 192x32 bf16 hi/lo (from pre-split ws copies)
#pragma unroll
        for (int it = 0; it < 3; ++it) {
            int vi = t + it * 256;            // 0..767
            int r = vi >> 2, kk = (vi & 3) * 8;
            *(short8*)&wb_hi[r][kk] = *(const short8*)(w_hi + (size_t)r * EMBED + e0 + kk);
            *(short8*)&wb_lo[r][kk] = *(const short8*)(w_lo + (size_t)r * EMBED + e0 + kk);
        }
        __syncthreads();

        short8 ah[2], al[2];
#pragma unroll
        for (int mt = 0; mt < 2; ++mt) {
            ah[mt] = *(const short8*)&xa_hi[wm * 32 + mt * 16 + ln][kg * 8];
            al[mt] = *(const short8*)&xa_lo[wm * 32 + mt * 16 + ln][kg * 8];
        }
#pragma unroll
        for (int nt = 0; nt < 6; ++nt) {
            const int ntg = 2 * nt + wn;
            short8 bh = *(const short8*)&wb_hi[ntg * 16 + ln][kg * 8];
            short8 bl = *(const short8*)&wb_lo[ntg * 16 + ln][kg * 8];
#pragma unroll
            for (int mt = 0; mt < 2; ++mt) {
                acc[mt][nt] = __builtin_amdgcn_mfma_f32_16x16x32_bf16(ah[mt], bh, acc[mt][nt], 0, 0, 0);
                if (ntg < 8) {  // q,k columns need the split correction terms
                    acc[mt][nt] = __builtin_amdgcn_mfma_f32_16x16x32_bf16(ah[mt], bl, acc[mt][nt], 0, 0, 0);
                    acc[mt][nt] = __builtin_amdgcn_mfma_f32_16x16x32_bf16(al[mt], bh, acc[mt][nt], 0, 0, 0);
                }
            }
        }
    }

    // epilogue: C layout col=lane&15, row=(lane>>4)*4+reg  [m89-verified]
#pragma unroll
    for (int mt = 0; mt < 2; ++mt) {
        const int rbase = row0 + wm * 32 + mt * 16 + kg * 4;
#pragma unroll
        for (int nt = 0; nt < 6; ++nt) {
            const int ntg = 2 * nt + wn;
            const int j = ntg * 16 + ln;
#pragma unroll
            for (int r = 0; r < 4; ++r) {
                float val = acc[mt][nt][r];
                int rg = rbase + r;
                int b = rg >> 11, s = rg & 2047;
                size_t rowoff = ((size_t)b * SEQ + s) * 64;
                if (j < 64) {
                    ushort h = f2bf(val);
                    q_hi[rowoff + j] = h;
                    q_lo[rowoff + j] = f2bf(val - bf2f(h));
                } else if (j < 128) {
                    ushort h = f2bf(val);
                    k_hi[rowoff + (j - 64)] = h;
                    k_lo[rowoff + (j - 64)] = f2bf(val - bf2f(h));
                } else {
                    v_t[((size_t)b * 64 + (j - 128)) * SEQ + s] = f2bf(val);
                }
            }
        }
    }
}

// ---------------------------------------------------------------------------
// Kernel 2: causal flash attention via MFMA.
// Block: 128 thr (2 waves).  Block handles balanced q-tile pair (qt, 63-qt)
// of 32 rows each -> nt(a)+nt(b) = 33 k-tiles of 64 keys.  Wave = 16 q-rows.
// QK^T: 3-product split-bf16 (q frags in registers, K hi/lo in LDS).
// Softmax in C-fragment layout, 16-lane shfl_xor reductions.
// PV: single bf16 product (P staged per-wave in LDS, V^T in LDS).
// ---------------------------------------------------------------------------
__global__ __launch_bounds__(128)
void attn_kernel(const ushort* __restrict__ q_hi, const ushort* __restrict__ q_lo,
                 const ushort* __restrict__ k_hi, const ushort* __restrict__ k_lo,
                 const ushort* __restrict__ v_t, float* __restrict__ out)
{
    __shared__ __align__(16) ushort kh[64][72], kl[64][72], vt[64][72]; // pad 64->72
    __shared__ __align__(16) ushort pT[2][16][72];

    const int t      = threadIdx.x;
    const int lane   = t & 63;
    const int wid    = t >> 6;        // 0,1
    const int ln     = lane & 15;
    const int kg     = lane >> 4;     // 0..3
    const int b      = blockIdx.x >> 5;
    const int pairid = blockIdx.x & 31;

    const ushort* qhb = q_hi + (size_t)b * SEQ * 64;
    const ushort* qlb = q_lo + (size_t)b * SEQ * 64;
    const ushort* khb = k_hi + (size_t)b * SEQ * 64;
    const ushort* klb = k_lo + (size_t)b * SEQ * 64;
    const ushort* vtb = v_t + (size_t)b * 64 * SEQ;
    float*        ob  = out + (size_t)b * SEQ * 64;

    const f32x4 vzero = {0.f, 0.f, 0.f, 0.f};

    for (int half = 0; half < 2; ++half) {
        const int qt  = half ? (63 - pairid) : pairid;
        const int r0  = qt * 32;
        const int r0w = r0 + wid * 16;

        // Q fragments (hi/lo, 2 k-steps) held in registers for the whole half
        short8 qh[2], ql[2];
#pragma unroll
        for (int ks = 0; ks < 2; ++ks) {
            size_t off = (size_t)(r0w + ln) * 64 + ks * 32 + kg * 8;
            qh[ks] = *(const short8*)(qhb + off);
            ql[ks] = *(const short8*)(qlb + off);
        }

        f32x4 o[4];
        float m_run[4], l_run[4];
#pragma unroll
        for (int i = 0; i < 4; ++i) { o[i] = vzero; m_run[i] = -INFINITY; l_run[i] = 0.f; }

        const int nt = qt / 2 + 1;
        for (int jt = 0; jt < nt; ++jt) {
            const int j0 = jt * 64;
            __syncthreads();   // prior tile's PV reads done (also guards half swap)
#pragma unroll
            for (int it = 0; it < 4; ++it) {
                int vi = t + it * 128;         // 0..511
                int r = vi >> 3, kk = (vi & 7) * 8;
                *(short8*)&kh[r][kk] = *(const short8*)(khb + (size_t)(j0 + r) * 64 + kk);
                *(short8*)&kl[r][kk] = *(const short8*)(klb + (size_t)(j0 + r) * 64 + kk);
                *(short8*)&vt[r][kk] = *(const short8*)(vtb + (size_t)r * SEQ + j0 + kk);
            }
            __syncthreads();

            // QK^T: 4 col-tiles x 2 k-steps x 3 split products
            f32x4 sacc[4];
#pragma unroll
            for (int ct = 0; ct < 4; ++ct) sacc[ct] = vzero;
#pragma unroll
            for (int ks = 0; ks < 2; ++ks) {
#pragma unroll
                for (int ct = 0; ct < 4; ++ct) {
                    short8 bh = *(const short8*)&kh[ct * 16 + ln][ks * 32 + kg * 8];
                    short8 bl = *(const short8*)&kl[ct * 16 + ln][ks * 32 + kg * 8];
                    sacc[ct] = __builtin_amdgcn_mfma_f32_16x16x32_bf16(qh[ks], bh, sacc[ct], 0, 0, 0);
                    sacc[ct] = __builtin_amdgcn_mfma_f32_16x16x32_bf16(qh[ks], bl, sacc[ct], 0, 0, 0);
                    sacc[ct] = __builtin_amdgcn_mfma_f32_16x16x32_bf16(ql[ks], bh, sacc[ct], 0, 0, 0);
                }
            }

            // causal mask (only the diagonal k-tile can clip)
            if (jt == nt - 1) {
#pragma unroll
                for (int ct = 0; ct < 4; ++ct) {
                    int col = j0 + ct * 16 + ln;
#pragma unroll
                    for (int r = 0; r < 4; ++r) {
                        int row = r0w + kg * 4 + r;
                        if (col > row) sacc[ct][r] = -1e30f;
                    }
                }
            }

            // online softmax per register-row; write P (bf16) to per-wave LDS
            float corr[4];
#pragma unroll
            for (int r = 0; r < 4; ++r) {
                float mt_ = fmaxf(fmaxf(sacc[0][r], sacc[1][r]), fmaxf(sacc[2][r], sacc[3][r]));
#pragma unroll
                for (int d = 1; d < 16; d <<= 1) mt_ = fmaxf(mt_, __shfl_xor(mt_, d));
                float mn = fmaxf(m_run[r], mt_);
                float c  = __expf(m_run[r] - mn);   // 0 on first tile
                float p0 = __expf(sacc[0][r] - mn);
                float p1 = __expf(sacc[1][r] - mn);
                float p2 = __expf(sacc[2][r] - mn);
                float p3 = __expf(sacc[3][r] - mn);
                float lt = (p0 + p1) + (p2 + p3);
#pragma unroll
                for (int d = 1; d < 16; d <<= 1) lt += __shfl_xor(lt, d);
                m_run[r] = mn;
                l_run[r] = l_run[r] * c + lt;
                corr[r]  = c;
                int prow = kg * 4 + r;
                pT[wid][prow][0 * 16 + ln] = f2bf(p0);
                pT[wid][prow][1 * 16 + ln] = f2bf(p1);
                pT[wid][prow][2 * 16 + ln] = f2bf(p2);
                pT[wid][prow][3 * 16 + ln] = f2bf(p3);
            }

            // rescale O, then accumulate PV (per-wave pT: no barrier needed)
#pragma unroll
            for (int ht = 0; ht < 4; ++ht)
#pragma unroll
                for (int r = 0; r < 4; ++r) o[ht][r] *= corr[r];

#pragma unroll
            for (int ks = 0; ks < 2; ++ks) {
                short8 pa = *(const short8*)&pT[wid][ln][ks * 32 + kg * 8];
#pragma unroll
                for (int ht = 0; ht < 4; ++ht) {
                    short8 bv = *(const short8*)&vt[ht * 16 + ln][ks * 32 + kg * 8];
                    o[ht] = __builtin_amdgcn_mfma_f32_16x16x32_bf16(pa, bv, o[ht], 0, 0, 0);
                }
            }
        }

        // epilogue: out[row][h] = o / l
#pragma unroll
        for (int ht = 0; ht < 4; ++ht) {
#pragma unroll
            for (int r = 0; r < 4; ++r) {
                int row = r0w + kg * 4 + r;
                ob[(size_t)row * 64 + ht * 16 + ln] = o[ht][r] / l_run[r];
            }
        }
    }
}

// ---------------------------------------------------------------------------
extern "C" void kernel_launch(void* const* d_in, const int* in_sizes, int n_in,
                              void* d_out, int out_size, void* d_ws, size_t ws_size,
                              hipStream_t stream)
{
    const float* x  = (const float*)d_in[0];
    const float* Wq = (const float*)d_in[1];
    const float* Wk = (const float*)d_in[2];
    const float* Wv = (const float*)d_in[3];
    float* out = (float*)d_out;

    ushort* ws = (ushort*)d_ws;
    ushort* w_hi = ws + WHI_OFF;
    ushort* w_lo = ws + WLO_OFF;
    ushort* q_hi = ws + QHI_OFF;
    ushort* q_lo = ws + QLO_OFF;
    ushort* k_hi = ws + KHI_OFF;
    ushort* k_lo = ws + KLO_OFF;
    ushort* v_t  = ws + VT_OFF;

    split_w_kernel<<<dim3(576), dim3(256), 0, stream>>>(Wq, Wk, Wv, w_hi, w_lo);
    proj_kernel<<<dim3(256), dim3(256), 0, stream>>>(x, w_hi, w_lo,
                                                     q_hi, q_lo, k_hi, k_lo, v_t);
    attn_kernel<<<dim3(256), dim3(128), 0, stream>>>(q_hi, q_lo, k_hi, k_lo, v_t, out);
}